// Round 1
// baseline (406.704 us; speedup 1.0000x reference)
//
#include <hip/hip_runtime.h>
#include <hip/hip_bf16.h>

// Problem: B=2,S=2048,D=1024,E=14,F=2048; N=4096 tokens.
// inputs: h (N,1024) f32, router_w (1024,14) f32, w1 (14,1024,2048) f32,
//         b1 (14,2048) f32, w2 (14,2048,1024) f32, b2 (14,1024) f32
// out: (N,1024) f32
//
// ws layout (ints): [0..16) cnt, [16..32) cursor, [32..48) offs, [48) ntiles,
// [64..160) tiles (e,m0)*45, [160..4256) assign, [4256..8352) wgt(f32),
// [8352..12576) list (4224). hid bf16 at byte 65536 (16.78 MB).

#define NTOK 4096
#define NEXP 14
#define DDIM 1024
#define FDIM 2048

typedef __attribute__((ext_vector_type(8))) short short8;
typedef __attribute__((ext_vector_type(4))) float floatx4;

__device__ __forceinline__ unsigned bfr(float f) {           // f32 -> bf16 bits, RNE
  unsigned u = __float_as_uint(f);
  return (u + 0x7FFFu + ((u >> 16) & 1u)) >> 16;
}
__device__ __forceinline__ unsigned pk2(float a, float b) {  // pack 2 bf16
  return bfr(a) | (bfr(b) << 16);
}

__global__ void k_init(int* wsI, int* list) {
  int i = blockIdx.x * 256 + threadIdx.x;
  if (i < 160) wsI[i] = 0;
  if (i < 4224) list[i] = 0;
}

// one wave per token: fp64 logits -> argmax + softmax weight + expert count
__global__ void k_router(const float* __restrict__ x, const float* __restrict__ rw,
                         int* __restrict__ assign, float* __restrict__ wgt,
                         int* __restrict__ cnt) {
  int wid = threadIdx.x >> 6, lane = threadIdx.x & 63;
  int n = blockIdx.x * 4 + wid;
  const float* xr = x + (size_t)n * DDIM;
  double acc[NEXP];
#pragma unroll
  for (int e = 0; e < NEXP; e++) acc[e] = 0.0;
  for (int d = lane; d < DDIM; d += 64) {
    float xv = xr[d];
    const float* rp = rw + (size_t)d * NEXP;
#pragma unroll
    for (int e = 0; e < NEXP; e++) acc[e] += (double)xv * (double)rp[e];
  }
#pragma unroll
  for (int e = 0; e < NEXP; e++)
    for (int m = 32; m > 0; m >>= 1) acc[e] += __shfl_xor(acc[e], m, 64);
  if (lane == 0) {
    int best = 0; double bv = acc[0];
    for (int e = 1; e < NEXP; e++) if (acc[e] > bv) { bv = acc[e]; best = e; }
    double s = 0.0;
    for (int e = 0; e < NEXP; e++) s += exp(acc[e] - bv);
    assign[n] = best;
    wgt[n] = (float)(1.0 / s);
    atomicAdd(&cnt[best], 1);
  }
}

__global__ void k_tiles(const int* __restrict__ cnt, int* __restrict__ offs,
                        int* __restrict__ tiles, int* __restrict__ ntl) {
  if (threadIdx.x == 0) {
    int off = 0, t = 0;
    for (int e = 0; e < NEXP; e++) { offs[e] = off; off += cnt[e]; }
    offs[NEXP] = off;
    for (int e = 0; e < NEXP; e++)
      for (int m0 = 0; m0 < cnt[e]; m0 += 128) { tiles[2 * t] = e; tiles[2 * t + 1] = m0; t++; }
    *ntl = t;
  }
}

__global__ void k_scatter(const int* __restrict__ assign, int* __restrict__ cursor,
                          const int* __restrict__ offs, int* __restrict__ list) {
  int n = blockIdx.x * 256 + threadIdx.x;
  if (n >= NTOK) return;
  int e = assign[n];
  int p = atomicAdd(&cursor[e], 1);
  list[offs[e] + p] = n;
}

// Grouped GEMM, tile 128x128, BK=64, 4 waves (each 64x64 = 4x4 frags of 16x16x32 bf16).
// LAYER 1: A = gathered x rows (f32->bf16), B = w1[e], epilogue GELU -> hid (bf16)
// LAYER 2: A = gathered hid rows (bf16),    B = w2[e], epilogue (+b2)*wgt -> out (f32)
template <int LAYER>
__global__ __launch_bounds__(256) void k_gemm(
    const float* __restrict__ Xf, const unsigned short* __restrict__ Xb,
    const float* __restrict__ W, const float* __restrict__ Bias,
    const float* __restrict__ wgt, unsigned short* __restrict__ outB,
    float* __restrict__ outF, const int* __restrict__ wsI) {
  constexpr int K = (LAYER == 1) ? DDIM : FDIM;
  constexpr int N = (LAYER == 1) ? FDIM : DDIM;
  const int* cnt = wsI;
  const int* offs = wsI + 32;
  const int* ntl = wsI + 48;
  const int* tiles = wsI + 64;
  const int* list = wsI + 8352;

  int tI = blockIdx.x;
  if (tI >= *ntl) return;
  int e = tiles[2 * tI], m0 = tiles[2 * tI + 1];
  int rows = cnt[e] - m0;
  int base = offs[e] + m0;
  int n0 = blockIdx.y * 128;

  __shared__ uint4 sAq[1024], sBq[1024];  // 16 KB each, bf16 [128 rows][64 k] XOR-swizzled
  __shared__ int tokL[128];
  __shared__ float wgtL[128];
  char* sA = (char*)sAq;
  char* sB = (char*)sBq;
  int tid = threadIdx.x;
  if (tid < 128) {
    int tok = list[base + tid];  // pad slots are zero-initialized -> token 0 (valid data)
    tokL[tid] = tok;
    if (LAYER == 2) wgtL[tid] = wgt[tok];
  }
  __syncthreads();

  int lane = tid & 63, wid = tid >> 6, wm = wid >> 1, wn = wid & 1;
  floatx4 acc[4][4];
#pragma unroll
  for (int i = 0; i < 4; i++)
#pragma unroll
    for (int j = 0; j < 4; j++) acc[i][j] = (floatx4){0.f, 0.f, 0.f, 0.f};

  const float* Wp = W + (size_t)e * K * N + n0;

  // hoist per-thread token indices for A staging (barriers block compiler hoisting)
  int tokA[8];
  if (LAYER == 1) {
#pragma unroll
    for (int j = 0; j < 8; j++) tokA[j] = tokL[(tid + j * 256) >> 4];
  } else {
#pragma unroll
    for (int j = 0; j < 4; j++) tokA[j] = tokL[(tid + j * 256) >> 3];
  }

  for (int k0 = 0; k0 < K; k0 += 64) {
    if (LAYER == 1) {
      // A: 128 rows x 64 k fp32 -> bf16. thread chunk = 1 row x 4 k (float4)
#pragma unroll
      for (int j = 0; j < 8; j++) {
        int lin = tid + j * 256;
        int row = lin >> 4, c4 = (lin & 15) * 4;
        float4 v = *(const float4*)(Xf + (size_t)tokA[j] * DDIM + k0 + c4);
        uint2 w2v;
        w2v.x = pk2(v.x, v.y);
        w2v.y = pk2(v.z, v.w);
        *(uint2*)(sA + row * 128 + ((c4 * 2) ^ ((row & 7) << 4))) = w2v;
      }
    } else {
      // A: bf16 rows, 16B chunks
#pragma unroll
      for (int j = 0; j < 4; j++) {
        int lin = tid + j * 256;
        int row = lin >> 3, b16 = (lin & 7) * 16;
        uint4 v = *(const uint4*)(Xb + (size_t)tokA[j] * FDIM + k0 + (b16 >> 1));
        *(uint4*)(sA + row * 128 + (b16 ^ ((row & 7) << 4))) = v;
      }
    }
    // B: transpose-stage w[k0..k0+64)[n0..n0+128) -> sB[n][k] bf16
#pragma unroll
    for (int j = 0; j < 8; j++) {
      int lin = tid + j * 256;
      int nn = lin & 127, k4 = (lin >> 7) * 4;
      const float* bp = Wp + (size_t)(k0 + k4) * N + nn;
      float v0 = bp[0], v1 = bp[N], v2 = bp[2 * (size_t)N], v3 = bp[3 * (size_t)N];
      uint2 w2v;
      w2v.x = pk2(v0, v1);
      w2v.y = pk2(v2, v3);
      *(uint2*)(sB + nn * 128 + ((k4 * 2) ^ ((nn & 7) << 4))) = w2v;
    }
    __syncthreads();
#pragma unroll
    for (int kc = 0; kc < 2; kc++) {
      short8 af[4], bf[4];
      int kb = kc * 64 + ((lane >> 4) << 4);
#pragma unroll
      for (int f = 0; f < 4; f++) {
        int rr = wm * 64 + f * 16 + (lane & 15);
        af[f] = *(const short8*)(sA + rr * 128 + (kb ^ ((rr & 7) << 4)));
        int cc = wn * 64 + f * 16 + (lane & 15);
        bf[f] = *(const short8*)(sB + cc * 128 + (kb ^ ((cc & 7) << 4)));
      }
#pragma unroll
      for (int fm = 0; fm < 4; fm++)
#pragma unroll
        for (int fn = 0; fn < 4; fn++)
          acc[fm][fn] = __builtin_amdgcn_mfma_f32_16x16x32_bf16(af[fm], bf[fn], acc[fm][fn], 0, 0, 0);
    }
    __syncthreads();
  }

  // epilogue. C frag mapping: col = lane&15, row = (lane>>4)*4 + r
  float bv[4];
#pragma unroll
  for (int f = 0; f < 4; f++) bv[f] = Bias[(size_t)e * N + n0 + wn * 64 + f * 16 + (lane & 15)];
#pragma unroll
  for (int fm = 0; fm < 4; fm++) {
#pragma unroll
    for (int r = 0; r < 4; r++) {
      int gr = wm * 64 + fm * 16 + ((lane >> 4) << 2) + r;
      if (gr < rows) {
        int tok = tokL[gr];
#pragma unroll
        for (int fn = 0; fn < 4; fn++) {
          int col = n0 + wn * 64 + fn * 16 + (lane & 15);
          float v = acc[fm][fn][r] + bv[fn];
          if (LAYER == 1) {
            v = 0.5f * v * (1.0f + erff(v * 0.70710678118654752f));  // exact GELU
            outB[(size_t)tok * FDIM + col] = (unsigned short)bfr(v);
          } else {
            outF[(size_t)tok * DDIM + col] = v * wgtL[gr];
          }
        }
      }
    }
  }
}

extern "C" void kernel_launch(void* const* d_in, const int* in_sizes, int n_in,
                              void* d_out, int out_size, void* d_ws, size_t ws_size,
                              hipStream_t stream) {
  const float* h  = (const float*)d_in[0];
  const float* rw = (const float*)d_in[1];
  const float* w1 = (const float*)d_in[2];
  const float* b1 = (const float*)d_in[3];
  const float* w2 = (const float*)d_in[4];
  const float* b2 = (const float*)d_in[5];
  float* out = (float*)d_out;

  int* wsI = (int*)d_ws;
  int* cnt = wsI;
  int* cursor = wsI + 16;
  int* offs = wsI + 32;
  int* ntl = wsI + 48;
  int* tiles = wsI + 64;
  int* assign = wsI + 160;
  float* wgt = (float*)(wsI + 4256);
  int* list = wsI + 8352;
  unsigned short* hid = (unsigned short*)((char*)d_ws + 65536);

  k_init<<<17, 256, 0, stream>>>(wsI, list);
  k_router<<<NTOK / 4, 256, 0, stream>>>(h, rw, assign, wgt, cnt);
  k_tiles<<<1, 64, 0, stream>>>(cnt, offs, tiles, ntl);
  k_scatter<<<NTOK / 256, 256, 0, stream>>>(assign, cursor, offs, list);
  // max tiles = 13 + ceil(4096/128) = 45
  k_gemm<1><<<dim3(45, FDIM / 128), 256, 0, stream>>>(h, nullptr, w1, b1, nullptr, hid, nullptr, wsI);
  k_gemm<2><<<dim3(45, DDIM / 128), 256, 0, stream>>>(nullptr, hid, w2, b2, wgt, nullptr, out, wsI);
}

// Round 2
// 384.181 us; speedup vs baseline: 1.0586x; 1.0586x over previous
//
#include <hip/hip_runtime.h>
#include <hip/hip_bf16.h>

// Problem: B=2,S=2048,D=1024,E=14,F=2048; N=4096 tokens.
// ws layout (ints): [0..16) cnt, [16..32) cursor, [32..48) offs, [48) ntiles,
// [64..160) tiles (e,m0)*45, [160..4256) assign, [4256..8352) wgt(f32),
// [8352..12576) list (4224). hid bf16 at byte 65536 (16.78 MB).

#define NTOK 4096
#define NEXP 14
#define DDIM 1024
#define FDIM 2048

typedef __attribute__((ext_vector_type(8))) short short8;
typedef __attribute__((ext_vector_type(4))) float floatx4;

__device__ __forceinline__ unsigned bfr(float f) {           // f32 -> bf16 bits, RNE
  unsigned u = __float_as_uint(f);
  return (u + 0x7FFFu + ((u >> 16) & 1u)) >> 16;
}
__device__ __forceinline__ unsigned pk2(float a, float b) {  // pack 2 bf16
  return bfr(a) | (bfr(b) << 16);
}

__global__ void k_init(int* wsI, int* list) {
  int i = blockIdx.x * 256 + threadIdx.x;
  if (i < 160) wsI[i] = 0;
  if (i < 4224) list[i] = 0;
}

// one wave per token: fp64 logits -> argmax + softmax weight + expert count
__global__ void k_router(const float* __restrict__ x, const float* __restrict__ rw,
                         int* __restrict__ assign, float* __restrict__ wgt,
                         int* __restrict__ cnt) {
  int wid = threadIdx.x >> 6, lane = threadIdx.x & 63;
  int n = blockIdx.x * 4 + wid;
  const float* xr = x + (size_t)n * DDIM;
  double acc[NEXP];
#pragma unroll
  for (int e = 0; e < NEXP; e++) acc[e] = 0.0;
  for (int d = lane; d < DDIM; d += 64) {
    float xv = xr[d];
    const float* rp = rw + (size_t)d * NEXP;
#pragma unroll
    for (int e = 0; e < NEXP; e++) acc[e] += (double)xv * (double)rp[e];
  }
#pragma unroll
  for (int e = 0; e < NEXP; e++)
    for (int m = 32; m > 0; m >>= 1) acc[e] += __shfl_xor(acc[e], m, 64);
  if (lane == 0) {
    int best = 0; double bv = acc[0];
    for (int e = 1; e < NEXP; e++) if (acc[e] > bv) { bv = acc[e]; best = e; }
    double s = 0.0;
    for (int e = 0; e < NEXP; e++) s += exp(acc[e] - bv);
    assign[n] = best;
    wgt[n] = (float)(1.0 / s);
    atomicAdd(&cnt[best], 1);
  }
}

__global__ void k_tiles(const int* __restrict__ cnt, int* __restrict__ offs,
                        int* __restrict__ tiles, int* __restrict__ ntl) {
  if (threadIdx.x == 0) {
    int off = 0, t = 0;
    for (int e = 0; e < NEXP; e++) { offs[e] = off; off += cnt[e]; }
    offs[NEXP] = off;
    for (int e = 0; e < NEXP; e++)
      for (int m0 = 0; m0 < cnt[e]; m0 += 128) { tiles[2 * t] = e; tiles[2 * t + 1] = m0; t++; }
    *ntl = t;
  }
}

__global__ void k_scatter(const int* __restrict__ assign, int* __restrict__ cursor,
                          const int* __restrict__ offs, int* __restrict__ list) {
  int n = blockIdx.x * 256 + threadIdx.x;
  if (n >= NTOK) return;
  int e = assign[n];
  int p = atomicAdd(&cursor[e], 1);
  list[offs[e] + p] = n;
}

// Grouped GEMM, tile 128xNT, BK=64, 4 waves (2x2), register-prefetch +
// double-buffered LDS + raw s_barrier (prefetch loads cross barrier un-drained).
// LAYER 1: NT=128. A = gathered x rows (f32->bf16), B = w1[e], GELU -> hid (bf16)
// LAYER 2: NT=64.  A = gathered hid rows (bf16),    B = w2[e], (+b2)*wgt -> out (f32)
template <int LAYER>
__global__ __launch_bounds__(256) void k_gemm(
    const float* __restrict__ Xf, const unsigned short* __restrict__ Xb,
    const float* __restrict__ W, const float* __restrict__ Bias,
    const float* __restrict__ wgt, unsigned short* __restrict__ outB,
    float* __restrict__ outF, const int* __restrict__ wsI) {
  constexpr int K = (LAYER == 1) ? DDIM : FDIM;
  constexpr int N = (LAYER == 1) ? FDIM : DDIM;
  constexpr int NT = (LAYER == 1) ? 128 : 64;  // n-tile
  constexpr int FN = NT / 32;                  // b-frags per wave
  constexpr int BCH = NT / 16;                 // B staging chunks per thread
  constexpr int NIT = K / 64;
  const int* cnt = wsI;
  const int* offs = wsI + 32;
  const int* ntl = wsI + 48;
  const int* tiles = wsI + 64;
  const int* list = wsI + 8352;

  int tI = blockIdx.x;
  if (tI >= *ntl) return;
  int e = tiles[2 * tI], m0 = tiles[2 * tI + 1];
  int rows = cnt[e] - m0;
  int base = offs[e] + m0;
  int n0 = blockIdx.y * NT;

  __shared__ uint4 sAq[2][1024];     // 2 x 16KB, bf16 [128][64] XOR-swizzled
  __shared__ uint4 sBq[2][NT * 8];   // 2 x NT*128B, bf16 [NT][64] XOR-swizzled
  __shared__ int tokL[128];
  __shared__ float wgtL[128];
  int tid = threadIdx.x;
  if (tid < 128) {
    int tok = list[base + tid];  // pad slots zero-initialized -> token 0 (valid data)
    tokL[tid] = tok;
    if (LAYER == 2) wgtL[tid] = wgt[tok];
  }
  __syncthreads();

  int lane = tid & 63, wid = tid >> 6, wm = wid >> 1, wn = wid & 1;
  floatx4 acc[4][FN];
#pragma unroll
  for (int i = 0; i < 4; i++)
#pragma unroll
    for (int j = 0; j < FN; j++) acc[i][j] = (floatx4){0.f, 0.f, 0.f, 0.f};

  const float* Wp = W + (size_t)e * K * N + n0;

  // hoist per-thread token row indices (barriers block compiler hoisting)
  int tokA[8];
  if (LAYER == 1) {
#pragma unroll
    for (int j = 0; j < 8; j++) tokA[j] = tokL[(tid + j * 256) >> 4];
  } else {
#pragma unroll
    for (int j = 0; j < 4; j++) tokA[j] = tokL[(tid + j * 256) >> 3];
  }

  // staging registers (next K-step in flight)
  float4 rA[8];
  uint4 rA4[4];
  float rB[BCH][4];

#define ISSUE_AB(k0)                                                                   \
  do {                                                                                 \
    if (LAYER == 1) {                                                                  \
      _Pragma("unroll") for (int j = 0; j < 8; j++) {                                  \
        int lin = tid + j * 256;                                                       \
        rA[j] = *(const float4*)(Xf + (size_t)tokA[j] * DDIM + (k0) + (lin & 15) * 4); \
      }                                                                                \
    } else {                                                                           \
      _Pragma("unroll") for (int j = 0; j < 4; j++) {                                  \
        int lin = tid + j * 256;                                                       \
        rA4[j] = *(const uint4*)(Xb + (size_t)tokA[j] * FDIM + (k0) + (lin & 7) * 8);  \
      }                                                                                \
    }                                                                                  \
    _Pragma("unroll") for (int j = 0; j < BCH; j++) {                                  \
      int lin = tid + j * 256;                                                         \
      int nn = lin & (NT - 1), k4 = (lin / NT) * 4;                                    \
      const float* bp = Wp + (size_t)((k0) + k4) * N + nn;                             \
      rB[j][0] = bp[0];                                                                \
      rB[j][1] = bp[N];                                                                \
      rB[j][2] = bp[2 * (size_t)N];                                                    \
      rB[j][3] = bp[3 * (size_t)N];                                                    \
    }                                                                                  \
  } while (0)

#define WRITE_AB(p)                                                                    \
  do {                                                                                 \
    char* sA_ = (char*)sAq[p];                                                         \
    char* sB_ = (char*)sBq[p];                                                         \
    if (LAYER == 1) {                                                                  \
      _Pragma("unroll") for (int j = 0; j < 8; j++) {                                  \
        int lin = tid + j * 256;                                                       \
        int row = lin >> 4, c8 = (lin & 15) * 8;                                       \
        uint2 w2v;                                                                     \
        w2v.x = pk2(rA[j].x, rA[j].y);                                                 \
        w2v.y = pk2(rA[j].z, rA[j].w);                                                 \
        *(uint2*)(sA_ + row * 128 + (c8 ^ ((row & 7) << 4))) = w2v;                    \
      }                                                                                \
    } else {                                                                           \
      _Pragma("unroll") for (int j = 0; j < 4; j++) {                                  \
        int lin = tid + j * 256;                                                       \
        int row = lin >> 3, b16 = (lin & 7) * 16;                                      \
        *(uint4*)(sA_ + row * 128 + (b16 ^ ((row & 7) << 4))) = rA4[j];                \
      }                                                                                \
    }                                                                                  \
    _Pragma("unroll") for (int j = 0; j < BCH; j++) {                                  \
      int lin = tid + j * 256;                                                         \
      int nn = lin & (NT - 1), k4 = (lin / NT) * 4;                                    \
      uint2 w2v;                                                                       \
      w2v.x = pk2(rB[j][0], rB[j][1]);                                                 \
      w2v.y = pk2(rB[j][2], rB[j][3]);                                                 \
      *(uint2*)(sB_ + nn * 128 + ((k4 * 2) ^ ((nn & 7) << 4))) = w2v;                  \
    }                                                                                  \
  } while (0)

  ISSUE_AB(0);
  for (int it = 0; it < NIT; ++it) {
    int p = it & 1;
    WRITE_AB(p);
    if (it + 1 < NIT) ISSUE_AB((it + 1) * 64);
    __builtin_amdgcn_sched_barrier(0);
    asm volatile("s_waitcnt lgkmcnt(0)" ::: "memory");
    __builtin_amdgcn_s_barrier();   // raw: prefetch loads stay in flight
    char* sA = (char*)sAq[p];
    char* sB = (char*)sBq[p];
#pragma unroll
    for (int kc = 0; kc < 2; kc++) {
      short8 af[4], bf[FN];
      int kb = kc * 64 + ((lane >> 4) << 4);
#pragma unroll
      for (int f = 0; f < 4; f++) {
        int rr = wm * 64 + f * 16 + (lane & 15);
        af[f] = *(const short8*)(sA + rr * 128 + (kb ^ ((rr & 7) << 4)));
      }
#pragma unroll
      for (int f = 0; f < FN; f++) {
        int cc = wn * (NT / 2) + f * 16 + (lane & 15);
        bf[f] = *(const short8*)(sB + cc * 128 + (kb ^ ((cc & 7) << 4)));
      }
#pragma unroll
      for (int fm = 0; fm < 4; fm++)
#pragma unroll
        for (int fn = 0; fn < FN; fn++)
          acc[fm][fn] = __builtin_amdgcn_mfma_f32_16x16x32_bf16(af[fm], bf[fn], acc[fm][fn], 0, 0, 0);
    }
  }

  // epilogue. C frag mapping: col = lane&15, row = (lane>>4)*4 + r
  float bv[FN];
#pragma unroll
  for (int f = 0; f < FN; f++) bv[f] = Bias[(size_t)e * N + n0 + wn * (NT / 2) + f * 16 + (lane & 15)];
#pragma unroll
  for (int fm = 0; fm < 4; fm++) {
#pragma unroll
    for (int r = 0; r < 4; r++) {
      int gr = wm * 64 + fm * 16 + ((lane >> 4) << 2) + r;
      if (gr < rows) {
        int tok = tokL[gr];
#pragma unroll
        for (int fn = 0; fn < FN; fn++) {
          int col = n0 + wn * (NT / 2) + fn * 16 + (lane & 15);
          float v = acc[fm][fn][r] + bv[fn];
          if (LAYER == 1) {
            v = 0.5f * v * (1.0f + erff(v * 0.70710678118654752f));  // exact GELU
            outB[(size_t)tok * FDIM + col] = (unsigned short)bfr(v);
          } else {
            outF[(size_t)tok * DDIM + col] = v * wgtL[gr];
          }
        }
      }
    }
  }
#undef ISSUE_AB
#undef WRITE_AB
}

extern "C" void kernel_launch(void* const* d_in, const int* in_sizes, int n_in,
                              void* d_out, int out_size, void* d_ws, size_t ws_size,
                              hipStream_t stream) {
  const float* h  = (const float*)d_in[0];
  const float* rw = (const float*)d_in[1];
  const float* w1 = (const float*)d_in[2];
  const float* b1 = (const float*)d_in[3];
  const float* w2 = (const float*)d_in[4];
  const float* b2 = (const float*)d_in[5];
  float* out = (float*)d_out;

  int* wsI = (int*)d_ws;
  int* assign = wsI + 160;
  float* wgt = (float*)(wsI + 4256);
  int* list = wsI + 8352;
  unsigned short* hid = (unsigned short*)((char*)d_ws + 65536);

  k_init<<<17, 256, 0, stream>>>(wsI, list);
  k_router<<<NTOK / 4, 256, 0, stream>>>(h, rw, assign, wgt, wsI);
  k_tiles<<<1, 64, 0, stream>>>(wsI, wsI + 32, wsI + 64, wsI + 48);
  k_scatter<<<NTOK / 256, 256, 0, stream>>>(assign, wsI + 16, wsI + 32, list);
  // max tiles = 13 + ceil(4096/128) = 45
  k_gemm<1><<<dim3(45, FDIM / 128), 256, 0, stream>>>(h, nullptr, w1, b1, nullptr, hid, nullptr, wsI);
  k_gemm<2><<<dim3(45, DDIM / 64), 256, 0, stream>>>(nullptr, hid, w2, b2, wgt, nullptr, out, wsI);
}

// Round 3
// 274.461 us; speedup vs baseline: 1.4818x; 1.3998x over previous
//
#include <hip/hip_runtime.h>
#include <hip/hip_bf16.h>

// Problem: B=2,S=2048,D=1024,E=14,F=2048; N=4096 tokens.
// ws layout (ints): [0..16) cnt, [16..32) cursor, [32..48) offs, [48) ntiles,
// [64..160) tiles (e,m0)*45, [160..4256) assign, [4256..8352) wgt(f32),
// [8352..12576) list (4224).
// hid bf16 at byte 65536 (16.78 MB); h16 bf16 at byte 65536+16777216 (8.39 MB).

#define NTOK 4096
#define NEXP 14
#define DDIM 1024
#define FDIM 2048

typedef __attribute__((ext_vector_type(8))) short short8;
typedef __attribute__((ext_vector_type(4))) float floatx4;

__device__ __forceinline__ unsigned bfr(float f) {  // f32 -> bf16 bits, RNE
  unsigned u = __float_as_uint(f);
  return (u + 0x7FFFu + ((u >> 16) & 1u)) >> 16;
}

__device__ __forceinline__ void gload16(const void* g, void* l) {
  __builtin_amdgcn_global_load_lds((const __attribute__((address_space(1))) void*)g,
                                   (__attribute__((address_space(3))) void*)l, 16, 0, 0);
}

__global__ void k_init(int* wsI, int* list) {
  int i = blockIdx.x * 256 + threadIdx.x;
  if (i < 160) wsI[i] = 0;
  if (i < 4224) list[i] = 0;
}

// one wave per token: fp64 logits -> argmax + softmax weight + expert count.
// Also emits h16 = bf16(h) for the MFMA A-path.
__global__ void k_router(const float* __restrict__ x, const float* __restrict__ rw,
                         int* __restrict__ assign, float* __restrict__ wgt,
                         int* __restrict__ cnt, unsigned short* __restrict__ h16) {
  int wid = threadIdx.x >> 6, lane = threadIdx.x & 63;
  int n = blockIdx.x * 4 + wid;
  const float* xr = x + (size_t)n * DDIM;
  unsigned short* hr = h16 + (size_t)n * DDIM;
  double acc[NEXP];
#pragma unroll
  for (int e = 0; e < NEXP; e++) acc[e] = 0.0;
  for (int d = lane; d < DDIM; d += 64) {
    float xv = xr[d];
    hr[d] = (unsigned short)bfr(xv);
    const float* rp = rw + (size_t)d * NEXP;
#pragma unroll
    for (int e = 0; e < NEXP; e++) acc[e] += (double)xv * (double)rp[e];
  }
#pragma unroll
  for (int e = 0; e < NEXP; e++)
    for (int m = 32; m > 0; m >>= 1) acc[e] += __shfl_xor(acc[e], m, 64);
  if (lane == 0) {
    int best = 0; double bv = acc[0];
    for (int e = 1; e < NEXP; e++) if (acc[e] > bv) { bv = acc[e]; best = e; }
    double s = 0.0;
    for (int e = 0; e < NEXP; e++) s += exp(acc[e] - bv);
    assign[n] = best;
    wgt[n] = (float)(1.0 / s);
    atomicAdd(&cnt[best], 1);
  }
}

__global__ void k_tiles(const int* __restrict__ cnt, int* __restrict__ offs,
                        int* __restrict__ tiles, int* __restrict__ ntl) {
  if (threadIdx.x == 0) {
    int off = 0, t = 0;
    for (int e = 0; e < NEXP; e++) { offs[e] = off; off += cnt[e]; }
    offs[NEXP] = off;
    for (int e = 0; e < NEXP; e++)
      for (int m0 = 0; m0 < cnt[e]; m0 += 128) { tiles[2 * t] = e; tiles[2 * t + 1] = m0; t++; }
    *ntl = t;
  }
}

__global__ void k_scatter(const int* __restrict__ assign, int* __restrict__ cursor,
                          const int* __restrict__ offs, int* __restrict__ list) {
  int n = blockIdx.x * 256 + threadIdx.x;
  if (n >= NTOK) return;
  int e = assign[n];
  int p = atomicAdd(&cursor[e], 1);
  list[offs[e] + p] = n;
}

// Grouped GEMM, tile 128x64, BK=64, 4 waves (2x2, each 64x32 = 4x2 frags).
// A (bf16 rows, gathered): global_load_lds direct-to-LDS, pre-swizzled per-lane
//   source addresses (linear LDS dest), zero staging registers.
// B (f32 weights): reg-staged transpose+convert (16 floats/thread), 1-deep prefetch.
// Double-buffered LDS, 2 raw barriers/iter, NO vmcnt drain: gloadA(it) is issued
// before B-reg loads(it), so WRITE_B's register wait retires A via vmcnt FIFO.
// LAYER 1: A=h16,  B=w1[e], epilogue exact-GELU -> hid (bf16)
// LAYER 2: A=hid,  B=w2[e], epilogue (+b2)*wgt  -> out (f32)
template <int LAYER>
__global__ __launch_bounds__(256, 3) void k_gemm(
    const unsigned short* __restrict__ Xb, const float* __restrict__ W,
    const float* __restrict__ Bias, const float* __restrict__ wgt,
    unsigned short* __restrict__ outB, float* __restrict__ outF,
    const int* __restrict__ wsI) {
  constexpr int K = (LAYER == 1) ? DDIM : FDIM;
  constexpr int N = (LAYER == 1) ? FDIM : DDIM;
  constexpr int NIT = K / 64;

  const int* cnt = wsI;
  const int* offs = wsI + 32;
  const int* ntl = wsI + 48;
  const int* tiles = wsI + 64;
  const int* list = wsI + 8352;

  int tI = blockIdx.x;
  if (tI >= *ntl) return;
  int e = tiles[2 * tI], m0 = tiles[2 * tI + 1];
  int rows = cnt[e] - m0;
  int base = offs[e] + m0;
  int n0 = blockIdx.y * 64;

  __shared__ char sA[2][16384];  // bf16 [128 rows][64 k], XOR-swizzled via source
  __shared__ char sB[2][8192];   // bf16 [64 cols][64 k], XOR-swizzled
  __shared__ int tokL[128];
  __shared__ float wgtL[128];

  int tid = threadIdx.x;
  if (tid < 128) {
    int tok = list[base + tid];  // pad slots zero-init -> token 0 (valid data)
    tokL[tid] = tok;
    if (LAYER == 2) wgtL[tid] = wgt[tok];
  }
  __syncthreads();

  int lane = tid & 63, wid = tid >> 6, wm = wid >> 1, wn = wid & 1;

  // A: per-lane pre-swizzled global source. Wave chunk c=wid*4+j covers rows
  // c*8..c*8+8; lane writes LDS row*128+(lane&7)*16, sources global byte
  // ((lane&7)*16) ^ ((row&7)<<4); row&7 == lane>>3.
  const char* gA[4];
  {
    unsigned sw = (unsigned)(((lane & 7) * 16) ^ ((lane >> 3) << 4));
#pragma unroll
    for (int j = 0; j < 4; j++) {
      int row = wid * 32 + j * 8 + (lane >> 3);
      gA[j] = (const char*)(Xb + (size_t)tokL[row] * K) + sw;
    }
  }

  // B: thread covers col nn = tid&63, k rows (tid>>6)*4 + j*16 + r
  int nn = tid & 63;
  int krow0 = (tid >> 6) * 4;
  const float* Wrow = W + (size_t)e * K * N + (size_t)krow0 * N + n0 + nn;

  floatx4 acc[4][2];
#pragma unroll
  for (int i = 0; i < 4; i++)
#pragma unroll
    for (int j = 0; j < 2; j++) acc[i][j] = (floatx4){0.f, 0.f, 0.f, 0.f};

  float rB[4][4];

#define ISSUE_B(k0)                                                \
  _Pragma("unroll") for (int j = 0; j < 4; j++)                    \
  _Pragma("unroll") for (int r = 0; r < 4; r++)                    \
      rB[j][r] = Wrow[(size_t)((k0) + j * 16 + r) * N];

#define WRITE_B(p)                                                                       \
  _Pragma("unroll") for (int j = 0; j < 4; j++) {                                        \
    uint2 wv;                                                                            \
    wv.x = bfr(rB[j][0]) | (bfr(rB[j][1]) << 16);                                        \
    wv.y = bfr(rB[j][2]) | (bfr(rB[j][3]) << 16);                                        \
    *(uint2*)(sB[p] + nn * 128 + (((krow0 + j * 16) * 2) ^ ((nn & 7) << 4))) = wv;       \
  }

#define GLOADA(k0, p)                                              \
  _Pragma("unroll") for (int j = 0; j < 4; j++)                    \
      gload16(gA[j] + (size_t)(k0) * 2, sA[p] + (wid * 4 + j) * 1024);

  GLOADA(0, 0);   // A before B: vmcnt FIFO invariant
  ISSUE_B(0);

  for (int it = 0; it < NIT; ++it) {
    int p = it & 1;
    __builtin_amdgcn_s_barrier();  // all reads of buf[p^1] (prev MFMA) done
    WRITE_B(p);                    // implicit vmcnt wait: retires gloadA(it) too
    __builtin_amdgcn_sched_barrier(0);
    if (it + 1 < NIT) {
      GLOADA((it + 1) * 64, p ^ 1);
      __builtin_amdgcn_sched_barrier(0);
      ISSUE_B((it + 1) * 64);
    }
    __builtin_amdgcn_sched_barrier(0);
    asm volatile("s_waitcnt lgkmcnt(0)" ::: "memory");  // sB[p] ds_writes visible
    __builtin_amdgcn_s_barrier();

    const char* A_ = sA[p];
    const char* B_ = sB[p];
#pragma unroll
    for (int kc = 0; kc < 2; kc++) {
      short8 af[4], bf[2];
      int kb = kc * 64 + ((lane >> 4) << 4);
#pragma unroll
      for (int f = 0; f < 4; f++) {
        int rr = wm * 64 + f * 16 + (lane & 15);
        af[f] = *(const short8*)(A_ + rr * 128 + (kb ^ ((rr & 7) << 4)));
      }
#pragma unroll
      for (int f = 0; f < 2; f++) {
        int cc = wn * 32 + f * 16 + (lane & 15);
        bf[f] = *(const short8*)(B_ + cc * 128 + (kb ^ ((cc & 7) << 4)));
      }
#pragma unroll
      for (int fm = 0; fm < 4; fm++)
#pragma unroll
        for (int fn = 0; fn < 2; fn++)
          acc[fm][fn] = __builtin_amdgcn_mfma_f32_16x16x32_bf16(af[fm], bf[fn], acc[fm][fn], 0, 0, 0);
    }
  }

  // epilogue. C frag mapping: col = lane&15, row = (lane>>4)*4 + r
  float bv[2];
#pragma unroll
  for (int f = 0; f < 2; f++) bv[f] = Bias[(size_t)e * N + n0 + wn * 32 + f * 16 + (lane & 15)];
#pragma unroll
  for (int fm = 0; fm < 4; fm++) {
#pragma unroll
    for (int r = 0; r < 4; r++) {
      int gr = wm * 64 + fm * 16 + ((lane >> 4) << 2) + r;
      if (gr < rows) {
        int tok = tokL[gr];
#pragma unroll
        for (int fn = 0; fn < 2; fn++) {
          int col = n0 + wn * 32 + fn * 16 + (lane & 15);
          float v = acc[fm][fn][r] + bv[fn];
          if (LAYER == 1) {
            v = 0.5f * v * (1.0f + erff(v * 0.70710678118654752f));  // exact GELU
            outB[(size_t)tok * FDIM + col] = (unsigned short)bfr(v);
          } else {
            outF[(size_t)tok * DDIM + col] = v * wgtL[gr];
          }
        }
      }
    }
  }
#undef ISSUE_B
#undef WRITE_B
#undef GLOADA
}

extern "C" void kernel_launch(void* const* d_in, const int* in_sizes, int n_in,
                              void* d_out, int out_size, void* d_ws, size_t ws_size,
                              hipStream_t stream) {
  const float* h  = (const float*)d_in[0];
  const float* rw = (const float*)d_in[1];
  const float* w1 = (const float*)d_in[2];
  const float* b1 = (const float*)d_in[3];
  const float* w2 = (const float*)d_in[4];
  const float* b2 = (const float*)d_in[5];
  float* out = (float*)d_out;

  int* wsI = (int*)d_ws;
  int* assign = wsI + 160;
  float* wgt = (float*)(wsI + 4256);
  int* list = wsI + 8352;
  unsigned short* hid = (unsigned short*)((char*)d_ws + 65536);
  unsigned short* h16 = (unsigned short*)((char*)d_ws + 65536 + 16777216);

  k_init<<<17, 256, 0, stream>>>(wsI, list);
  k_router<<<NTOK / 4, 256, 0, stream>>>(h, rw, assign, wgt, wsI, h16);
  k_tiles<<<1, 64, 0, stream>>>(wsI, wsI + 32, wsI + 64, wsI + 48);
  k_scatter<<<NTOK / 256, 256, 0, stream>>>(assign, wsI + 16, wsI + 32, list);
  // max tiles = 13 + ceil(4096/128) = 45
  k_gemm<1><<<dim3(45, FDIM / 64), 256, 0, stream>>>(h16, w1, b1, nullptr, hid, nullptr, wsI);
  k_gemm<2><<<dim3(45, DDIM / 64), 256, 0, stream>>>(hid, w2, b2, wgt, nullptr, out, wsI);
}

// Round 4
// 270.412 us; speedup vs baseline: 1.5040x; 1.0150x over previous
//
#include <hip/hip_runtime.h>
#include <hip/hip_bf16.h>

// Problem: B=2,S=2048,D=1024,E=14,F=2048; N=4096 tokens.
// ws layout (ints): [0..16) cnt, [16..32) cursor, [32..48) offs, [48) ntiles,
// [64..160) tiles (e,m0)*45, [160..4256) assign, [4256..8352) wgt(f32),
// [8352..12576) list (4224).
// hid bf16 at byte 65536 (16.78 MB); h16 bf16 at byte 65536+16777216 (8.39 MB).

#define NTOK 4096
#define NEXP 14
#define DDIM 1024
#define FDIM 2048

typedef __attribute__((ext_vector_type(8))) short short8;
typedef __attribute__((ext_vector_type(4))) float floatx4;

__device__ __forceinline__ unsigned bfr(float f) {  // f32 -> bf16 bits, RNE
  unsigned u = __float_as_uint(f);
  return (u + 0x7FFFu + ((u >> 16) & 1u)) >> 16;
}

__device__ __forceinline__ void gload16(const void* g, void* l) {
  __builtin_amdgcn_global_load_lds((const __attribute__((address_space(1))) void*)g,
                                   (__attribute__((address_space(3))) void*)l, 16, 0, 0);
}

__global__ void k_init(int* wsI, int* list) {
  int i = blockIdx.x * 256 + threadIdx.x;
  if (i < 160) wsI[i] = 0;
  if (i < 4224) list[i] = 0;
}

// one wave per token: fp64 logits -> argmax + softmax weight + expert count.
// Also emits h16 = bf16(h) for the MFMA A-path.
__global__ void k_router(const float* __restrict__ x, const float* __restrict__ rw,
                         int* __restrict__ assign, float* __restrict__ wgt,
                         int* __restrict__ cnt, unsigned short* __restrict__ h16) {
  int wid = threadIdx.x >> 6, lane = threadIdx.x & 63;
  int n = blockIdx.x * 4 + wid;
  const float* xr = x + (size_t)n * DDIM;
  unsigned short* hr = h16 + (size_t)n * DDIM;
  double acc[NEXP];
#pragma unroll
  for (int e = 0; e < NEXP; e++) acc[e] = 0.0;
  for (int d = lane; d < DDIM; d += 64) {
    float xv = xr[d];
    hr[d] = (unsigned short)bfr(xv);
    const float* rp = rw + (size_t)d * NEXP;
#pragma unroll
    for (int e = 0; e < NEXP; e++) acc[e] += (double)xv * (double)rp[e];
  }
#pragma unroll
  for (int e = 0; e < NEXP; e++)
    for (int m = 32; m > 0; m >>= 1) acc[e] += __shfl_xor(acc[e], m, 64);
  if (lane == 0) {
    int best = 0; double bv = acc[0];
    for (int e = 1; e < NEXP; e++) if (acc[e] > bv) { bv = acc[e]; best = e; }
    double s = 0.0;
    for (int e = 0; e < NEXP; e++) s += exp(acc[e] - bv);
    assign[n] = best;
    wgt[n] = (float)(1.0 / s);
    atomicAdd(&cnt[best], 1);
  }
}

__global__ void k_tiles(const int* __restrict__ cnt, int* __restrict__ offs,
                        int* __restrict__ tiles, int* __restrict__ ntl) {
  if (threadIdx.x == 0) {
    int off = 0, t = 0;
    for (int e = 0; e < NEXP; e++) { offs[e] = off; off += cnt[e]; }
    offs[NEXP] = off;
    for (int e = 0; e < NEXP; e++)
      for (int m0 = 0; m0 < cnt[e]; m0 += 128) { tiles[2 * t] = e; tiles[2 * t + 1] = m0; t++; }
    *ntl = t;
  }
}

__global__ void k_scatter(const int* __restrict__ assign, int* __restrict__ cursor,
                          const int* __restrict__ offs, int* __restrict__ list) {
  int n = blockIdx.x * 256 + threadIdx.x;
  if (n >= NTOK) return;
  int e = assign[n];
  int p = atomicAdd(&cursor[e], 1);
  list[offs[e] + p] = n;
}

// Grouped GEMM, tile 128x64, BK=64, 4 waves (2x2, each 64x32 = 4x2 frags).
// A (bf16 rows, gathered): global_load_lds direct-to-LDS, pre-swizzled per-lane
//   source addresses (linear LDS dest), zero staging registers.
// B (f32 weights): reg-staged transpose+convert (16 floats/thread), 1-deep prefetch.
// Double-buffered LDS, 2 raw barriers/iter, NO vmcnt drain: gloadA(it) is issued
// before B-reg loads(it), so WRITE_B's register wait retires A via vmcnt FIFO.
// LAYER 1: A=h16,  B=w1[e], epilogue exact-GELU -> hid (bf16)
// LAYER 2: A=hid,  B=w2[e], epilogue (+b2)*wgt  -> out (f32)
template <int LAYER>
__global__ __launch_bounds__(256, 3) void k_gemm(
    const unsigned short* __restrict__ Xb, const float* __restrict__ W,
    const float* __restrict__ Bias, const float* __restrict__ wgt,
    unsigned short* __restrict__ outB, float* __restrict__ outF,
    const int* __restrict__ wsI) {
  constexpr int K = (LAYER == 1) ? DDIM : FDIM;
  constexpr int N = (LAYER == 1) ? FDIM : DDIM;
  constexpr int NIT = K / 64;

  const int* cnt = wsI;
  const int* offs = wsI + 32;
  const int* ntl = wsI + 48;
  const int* tiles = wsI + 64;
  const int* list = wsI + 8352;

  int tI = blockIdx.x;
  if (tI >= *ntl) return;
  int e = tiles[2 * tI], m0 = tiles[2 * tI + 1];
  int rows = cnt[e] - m0;
  int base = offs[e] + m0;
  int n0 = blockIdx.y * 64;

  __shared__ char sA[2][16384];  // bf16 [128 rows][64 k], XOR-swizzled via source
  __shared__ char sB[2][8192];   // bf16 [64 cols][64 k], XOR-swizzled
  __shared__ int tokL[128];
  __shared__ float wgtL[128];

  int tid = threadIdx.x;
  if (tid < 128) {
    int tok = list[base + tid];  // pad slots zero-init -> token 0 (valid data)
    tokL[tid] = tok;
    if (LAYER == 2) wgtL[tid] = wgt[tok];
  }
  __syncthreads();

  int lane = tid & 63, wid = tid >> 6, wm = wid >> 1, wn = wid & 1;

  // A: per-lane pre-swizzled global source. Wave chunk c=wid*4+j covers rows
  // c*8..c*8+8; lane writes LDS row*128+(lane&7)*16, sources global byte
  // ((lane&7)*16) ^ ((row&7)<<4); row&7 == lane>>3.
  const char* gA[4];
  {
    unsigned sw = (unsigned)(((lane & 7) * 16) ^ ((lane >> 3) << 4));
#pragma unroll
    for (int j = 0; j < 4; j++) {
      int row = wid * 32 + j * 8 + (lane >> 3);
      gA[j] = (const char*)(Xb + (size_t)tokL[row] * K) + sw;
    }
  }

  // B: thread covers col nn = tid&63, k rows (tid>>6)*4 + j*16 + r
  int nn = tid & 63;
  int krow0 = (tid >> 6) * 4;
  const float* Wrow = W + (size_t)e * K * N + (size_t)krow0 * N + n0 + nn;

  floatx4 acc[4][2];
#pragma unroll
  for (int i = 0; i < 4; i++)
#pragma unroll
    for (int j = 0; j < 2; j++) acc[i][j] = (floatx4){0.f, 0.f, 0.f, 0.f};

  float rB[4][4];

#define ISSUE_B(k0)                                                \
  _Pragma("unroll") for (int j = 0; j < 4; j++)                    \
  _Pragma("unroll") for (int r = 0; r < 4; r++)                    \
      rB[j][r] = Wrow[(size_t)((k0) + j * 16 + r) * N];

#define WRITE_B(p)                                                                       \
  _Pragma("unroll") for (int j = 0; j < 4; j++) {                                        \
    uint2 wv;                                                                            \
    wv.x = bfr(rB[j][0]) | (bfr(rB[j][1]) << 16);                                        \
    wv.y = bfr(rB[j][2]) | (bfr(rB[j][3]) << 16);                                        \
    *(uint2*)(sB[p] + nn * 128 + (((krow0 + j * 16) * 2) ^ ((nn & 7) << 4))) = wv;       \
  }

#define GLOADA(k0, p)                                              \
  _Pragma("unroll") for (int j = 0; j < 4; j++)                    \
      gload16(gA[j] + (size_t)(k0) * 2, sA[p] + (wid * 4 + j) * 1024);

  GLOADA(0, 0);   // A before B: vmcnt FIFO invariant
  ISSUE_B(0);

  for (int it = 0; it < NIT; ++it) {
    int p = it & 1;
    __builtin_amdgcn_s_barrier();  // all reads of buf[p^1] (prev MFMA) done
    WRITE_B(p);                    // implicit vmcnt wait: retires gloadA(it) too
    __builtin_amdgcn_sched_barrier(0);
    if (it + 1 < NIT) {
      GLOADA((it + 1) * 64, p ^ 1);
      __builtin_amdgcn_sched_barrier(0);
      ISSUE_B((it + 1) * 64);
    }
    __builtin_amdgcn_sched_barrier(0);
    asm volatile("s_waitcnt lgkmcnt(0)" ::: "memory");  // sB[p] ds_writes visible
    __builtin_amdgcn_s_barrier();

    const char* A_ = sA[p];
    const char* B_ = sB[p];
#pragma unroll
    for (int kc = 0; kc < 2; kc++) {
      short8 af[4], bf[2];
      int kb = kc * 64 + ((lane >> 4) << 4);
#pragma unroll
      for (int f = 0; f < 4; f++) {
        int rr = wm * 64 + f * 16 + (lane & 15);
        af[f] = *(const short8*)(A_ + rr * 128 + (kb ^ ((rr & 7) << 4)));
      }
#pragma unroll
      for (int f = 0; f < 2; f++) {
        int cc = wn * 32 + f * 16 + (lane & 15);
        bf[f] = *(const short8*)(B_ + cc * 128 + (kb ^ ((cc & 7) << 4)));
      }
#pragma unroll
      for (int fm = 0; fm < 4; fm++)
#pragma unroll
        for (int fn = 0; fn < 2; fn++)
          acc[fm][fn] = __builtin_amdgcn_mfma_f32_16x16x32_bf16(af[fm], bf[fn], acc[fm][fn], 0, 0, 0);
    }
  }

  // epilogue. C frag mapping: col = lane&15, row = (lane>>4)*4 + r
  float bv[2];
#pragma unroll
  for (int f = 0; f < 2; f++) bv[f] = Bias[(size_t)e * N + n0 + wn * 32 + f * 16 + (lane & 15)];
#pragma unroll
  for (int fm = 0; fm < 4; fm++) {
#pragma unroll
    for (int r = 0; r < 4; r++) {
      int gr = wm * 64 + fm * 16 + ((lane >> 4) << 2) + r;
      if (gr < rows) {
        int tok = tokL[gr];
#pragma unroll
        for (int fn = 0; fn < 2; fn++) {
          int col = n0 + wn * 32 + fn * 16 + (lane & 15);
          float v = acc[fm][fn][r] + bv[fn];
          if (LAYER == 1) {
            v = 0.5f * v * (1.0f + erff(v * 0.70710678118654752f));  // exact GELU
            outB[(size_t)tok * FDIM + col] = (unsigned short)bfr(v);
          } else {
            outF[(size_t)tok * DDIM + col] = v * wgtL[gr];
          }
        }
      }
    }
  }
#undef ISSUE_B
#undef WRITE_B
#undef GLOADA
}

extern "C" void kernel_launch(void* const* d_in, const int* in_sizes, int n_in,
                              void* d_out, int out_size, void* d_ws, size_t ws_size,
                              hipStream_t stream) {
  const float* h  = (const float*)d_in[0];
  const float* rw = (const float*)d_in[1];
  const float* w1 = (const float*)d_in[2];
  const float* b1 = (const float*)d_in[3];
  const float* w2 = (const float*)d_in[4];
  const float* b2 = (const float*)d_in[5];
  float* out = (float*)d_out;

  int* wsI = (int*)d_ws;
  int* assign = wsI + 160;
  float* wgt = (float*)(wsI + 4256);
  int* list = wsI + 8352;
  unsigned short* hid = (unsigned short*)((char*)d_ws + 65536);
  unsigned short* h16 = (unsigned short*)((char*)d_ws + 65536 + 16777216);

  k_init<<<17, 256, 0, stream>>>(wsI, list);
  k_router<<<NTOK / 4, 256, 0, stream>>>(h, rw, assign, wgt, wsI, h16);
  k_tiles<<<1, 64, 0, stream>>>(wsI, wsI + 32, wsI + 64, wsI + 48);
  k_scatter<<<NTOK / 256, 256, 0, stream>>>(assign, wsI + 16, wsI + 32, list);
  // max tiles = 13 + ceil(4096/128) = 45
  k_gemm<1><<<dim3(45, FDIM / 64), 256, 0, stream>>>(h16, w1, b1, nullptr, hid, nullptr, wsI);
  k_gemm<2><<<dim3(45, DDIM / 64), 256, 0, stream>>>(hid, w2, b2, wgt, nullptr, out, wsI);
}